// Round 12
// baseline (108.434 us; speedup 1.0000x reference)
//
#include <hip/hip_runtime.h>

#define IMG_SIZE 256
#define NPIX (IMG_SIZE * IMG_SIZE)
#define KSEL 5
#define BS 8
#define LL 64
#define LUSED 63          // row l=63's top-k is discarded by the roll — never compute/write it
#define NTHREADS 256
#define SPLIT 4           // chunk splits per image
#define CHUNK (NPIX / SPLIT)      // 16384 pixels per (b,split) slice
#define RPB 4             // rows (l values) amortized per block
#define RGRP (LL / RPB)   // 16 row-groups (l = rg*4+r; l=63 computed, never written)
#define NBLK2 (BS * SPLIT * RGRP)         // 512 blocks = 2/CU, fully co-resident
#define QCAP 1536         // per-wave tagged candidate queue (u64)
#define SENTK 0xFFFFFFFFFFFFFFFFULL

typedef unsigned long long ull;

// Branchless sorted-insert: loc[] ascending; bubble key in, evict the max.
// Static indices only -> stays in VGPRs; no divergence.
__device__ __forceinline__ void sort_insert(ull loc[KSEL], ull key) {
    #pragma unroll
    for (int j = 0; j < KSEL; ++j) {
        const ull a = loc[j];
        const bool lt = key < a;
        loc[j] = lt ? key : a;
        key    = lt ? a : key;
    }
}

// Merge two ascending 5-lists, keep smallest 5 into a.
__device__ __forceinline__ void merge5(ull* a, const ull* b) {
    ull out[KSEL];
    int ia = 0, ib = 0;
    #pragma unroll
    for (int j = 0; j < KSEL; ++j) {
        const ull va = a[ia], vb = b[ib];
        const bool ta = va <= vb;
        out[j] = ta ? va : vb;
        ia += ta ? 1 : 0;
        ib += ta ? 0 : 1;
    }
    #pragma unroll
    for (int j = 0; j < KSEL; ++j) a[j] = out[j];
}

// Single source of truth for the SSD: match numpy f32 exactly — no FMA
// contraction, ((d0^2+d1^2)+d2^2). Bootstrap keys and steady-path gate both
// use THIS function, so gate-s and key-s are bit-identical.
__device__ __forceinline__ float
pix_s(float r0, float r1, float r2, float c0, float c1, float c2) {
    float d0 = __fsub_rn(r0, c0);
    float d1 = __fsub_rn(r1, c1);
    float d2 = __fsub_rn(r2, c2);
    return __fadd_rn(__fadd_rn(__fmul_rn(d0, d0), __fmul_rn(d1, d1)), __fmul_rn(d2, d2));
}

__device__ __forceinline__ ull
pix_key(float r0, float r1, float r2, float c0, float c1, float c2, int pix) {
    // s >= 0 (sum of squares) -> uint bit order == float order; low bits = pixel
    // index gives jax top_k's lower-index-first tie-break.
    const float s = pix_s(r0, r1, r2, c0, c1, c2);
    return ((ull)__float_as_uint(s) << 32) | (unsigned int)pix;
}

// One block per (b, split, row-group of RPB l's). Verified R9 pipeline per row
// (bootstrap -> block-exact threshold -> gate-to-memory steady loop -> drain
// -> merge tree), with the image loads AMORTIZED over RPB=4 rows: L2 read
// volume drops 4x (396 -> 99 MB) while total VALU is unchanged. No XCD
// swizzle (R11 refuted the %8 mapping), no cross-block sync (R10), no
// divergent insert in the steady path (R7/R8).
// Queue entries carry a 2-bit row tag at bits 16-17 (pix < 2^16); the pure
// key is reconstructed on drain and inserted via a static if-chain (keeps
// loc[][] in registers). Exactness per row r (as verified in R8/R9):
//   thr[r] = bits of 5th-smallest s over the 1024-px bootstrap >= s5_chunk;
//   admit iff bits(s) <= thr[r] => every true top-5 key is in bootstrap∪queue;
//   each pixel tested once per row, each queue entry inserted once
//   => bit-identical top-5 per (row, split).
__global__ __launch_bounds__(NTHREADS, 2)
void topk_kernel(const float* __restrict__ preds,
                 const float* __restrict__ imgs,
                 ull* __restrict__ keys_out) {
    const int blk = blockIdx.x;
    const int split = blk & (SPLIT - 1);
    const int q2 = blk >> 2;
    const int b = q2 & (BS - 1);
    const int rg = q2 >> 3;              // 0 .. RGRP-1
    const int t = threadIdx.x;
    const int wave = t >> 6;
    const int lane = t & 63;

    __shared__ union ShMem {
        ull qq[4][QCAP];                 // 49152 B: per-wave tagged queues
        ull sk[NTHREADS * KSEL];         // 10240 B: merge scratch (aliases qq[0][...])
    } shm;
    __shared__ unsigned wcnt[4];

    if (t < 4) wcnt[t] = 0u;

    const float* imgb = imgs + (size_t)b * 3 * NPIX;

    // Per-row pooled colors (verified scrambled indexing: flat i = l*bs + b).
    float c0v[RPB], c1v[RPB], c2v[RPB];
    #pragma unroll
    for (int r = 0; r < RPB; ++r) {
        const int l = rg * RPB + r;      // l = 63 computed, never written
        const int i = l * BS + b;
        const int pb = i >> 6;
        const int pl = i & 63;
        const float px = preds[pb * (LL * 8) + pl * 8 + 0];
        const float py = preds[pb * (LL * 8) + pl * 8 + 1];
        // grid_sample nearest, align_corners=False, zeros padding.
        const float cx = __fsub_rn(__fmul_rn(px, 256.0f), 0.5f);
        const float cy = __fsub_rn(__fmul_rn(py, 256.0f), 0.5f);
        const int ix = (int)rintf(cx);   // round half to even == jnp.rint
        const int iy = (int)rintf(cy);
        const bool valid = (ix >= 0) && (ix < IMG_SIZE) && (iy >= 0) && (iy < IMG_SIZE);
        const int ixc = min(max(ix, 0), IMG_SIZE - 1);
        const int iyc = min(max(iy, 0), IMG_SIZE - 1);
        const float vmul = valid ? 1.0f : 0.0f;
        c0v[r] = imgb[0 * NPIX + iyc * IMG_SIZE + ixc] * vmul;
        c1v[r] = imgb[1 * NPIX + iyc * IMG_SIZE + ixc] * vmul;
        c2v[r] = imgb[2 * NPIX + iyc * IMG_SIZE + ixc] * vmul;
    }

    const float4* p0 = (const float4*)(imgb + 0 * NPIX);
    const float4* p1 = (const float4*)(imgb + 1 * NPIX);
    const float4* p2 = (const float4*)(imgb + 2 * NPIX);

    ull loc[RPB][KSEL];                  // all row loops unrolled -> registers
    #pragma unroll
    for (int r = 0; r < RPB; ++r)
        #pragma unroll
        for (int j = 0; j < KSEL; ++j) loc[r][j] = SENTK;

    const int v0 = split * (CHUNK / 4);

    // ---- Bootstrap: iteration 0 (1024 px), unconditional inserts x 4 rows ----
    {
        const int v = v0 + t;
        const float4 r0 = p0[v];
        const float4 r1 = p1[v];
        const float4 r2 = p2[v];
        const int base = v * 4;
        #pragma unroll
        for (int r = 0; r < RPB; ++r) {
            sort_insert(loc[r], pix_key(r0.x, r1.x, r2.x, c0v[r], c1v[r], c2v[r], base + 0));
            sort_insert(loc[r], pix_key(r0.y, r1.y, r2.y, c0v[r], c1v[r], c2v[r], base + 1));
            sort_insert(loc[r], pix_key(r0.z, r1.z, r2.z, c0v[r], c1v[r], c2v[r], base + 2));
            sort_insert(loc[r], pix_key(r0.w, r1.w, r2.w, c0v[r], c1v[r], c2v[r], base + 3));
        }
    }

    // ---- Per-row block-exact bootstrap thresholds (verified merge5 tree x4) ----
    unsigned thrv[RPB];
    __syncthreads();                     // wcnt init + before first sk use
    #pragma unroll
    for (int r = 0; r < RPB; ++r) {
        #pragma unroll
        for (int j = 0; j < KSEL; ++j) shm.sk[t * KSEL + j] = loc[r][j];
        __syncthreads();
        for (int s = NTHREADS / 2; s > 0; s >>= 1) {
            if (t < s) {
                ull a[KSEL], bb[KSEL];
                #pragma unroll
                for (int j = 0; j < KSEL; ++j) { a[j] = shm.sk[t * KSEL + j]; bb[j] = shm.sk[(t + s) * KSEL + j]; }
                merge5(a, bb);
                #pragma unroll
                for (int j = 0; j < KSEL; ++j) shm.sk[t * KSEL + j] = a[j];
            }
            __syncthreads();
        }
        thrv[r] = (unsigned)(shm.sk[KSEL - 1] >> 32);   // bits of s5(bootstrap, row r)
        __syncthreads();                 // all read sk[4] before next overwrite
    }
    if (t < 4) wcnt[t] = 0u;             // queue region (aliases sk) about to be used
    __syncthreads();

    // Drain helper: pop tagged entries into the right row list (static if-chain).
    auto drain = [&]() {
        const unsigned n = wcnt[wave];
        for (unsigned o = lane; o < n; o += 64) {
            const ull e = shm.qq[wave][o];
            const ull key = (e & 0xFFFFFFFF00000000ULL) | (e & 0xFFFFULL);
            const int tg = (int)((e >> 16) & 3ULL);
            if (tg == 0)      sort_insert(loc[0], key);
            else if (tg == 1) sort_insert(loc[1], key);
            else if (tg == 2) sort_insert(loc[2], key);
            else              sort_insert(loc[3], key);
        }
    };

    // ---- Steady loop: dense loads amortized over 4 rows; 9-op s per row;
    //      rare tagged queue push (no insert, no ballot in the hot path) ----
    #pragma unroll 2
    for (int it = 1; it < CHUNK / 4 / NTHREADS; ++it) {
        // Overflow safety (wave-uniform; worst case 64*4px*4rows = 1024 pushes/iter).
        if (wcnt[wave] > QCAP - 4 * NTHREADS) {
            drain();
            if (lane == 0) wcnt[wave] = 0u;   // per-wave LDS ops in order: reads precede
        }
        const int v = v0 + it * NTHREADS + t;
        const float4 r0 = p0[v];
        const float4 r1 = p1[v];
        const float4 r2 = p2[v];
        const int base = v * 4;

        #pragma unroll
        for (int r = 0; r < RPB; ++r) {
            const float s0 = pix_s(r0.x, r1.x, r2.x, c0v[r], c1v[r], c2v[r]);
            const float s1 = pix_s(r0.y, r1.y, r2.y, c0v[r], c1v[r], c2v[r]);
            const float s2 = pix_s(r0.z, r1.z, r2.z, c0v[r], c1v[r], c2v[r]);
            const float s3 = pix_s(r0.w, r1.w, r2.w, c0v[r], c1v[r], c2v[r]);
            if (__float_as_uint(s0) <= thrv[r]) {
                const unsigned pos = atomicAdd(&wcnt[wave], 1u);
                shm.qq[wave][pos] = ((ull)__float_as_uint(s0) << 32) | ((ull)r << 16) | (unsigned)(base + 0);
            }
            if (__float_as_uint(s1) <= thrv[r]) {
                const unsigned pos = atomicAdd(&wcnt[wave], 1u);
                shm.qq[wave][pos] = ((ull)__float_as_uint(s1) << 32) | ((ull)r << 16) | (unsigned)(base + 1);
            }
            if (__float_as_uint(s2) <= thrv[r]) {
                const unsigned pos = atomicAdd(&wcnt[wave], 1u);
                shm.qq[wave][pos] = ((ull)__float_as_uint(s2) << 32) | ((ull)r << 16) | (unsigned)(base + 2);
            }
            if (__float_as_uint(s3) <= thrv[r]) {
                const unsigned pos = atomicAdd(&wcnt[wave], 1u);
                shm.qq[wave][pos] = ((ull)__float_as_uint(s3) << 32) | ((ull)r << 16) | (unsigned)(base + 3);
            }
        }
    }

    // ---- End drain, then per-row verified merge trees + key output ----
    drain();
    __syncthreads();                     // all drains done before sk (alias) reuse
    #pragma unroll
    for (int r = 0; r < RPB; ++r) {
        const int l = rg * RPB + r;
        #pragma unroll
        for (int j = 0; j < KSEL; ++j) shm.sk[t * KSEL + j] = loc[r][j];
        __syncthreads();
        for (int s = NTHREADS / 2; s > 0; s >>= 1) {
            if (t < s) {
                ull a[KSEL], bb[KSEL];
                #pragma unroll
                for (int j = 0; j < KSEL; ++j) { a[j] = shm.sk[t * KSEL + j]; bb[j] = shm.sk[(t + s) * KSEL + j]; }
                merge5(a, bb);
                #pragma unroll
                for (int j = 0; j < KSEL; ++j) shm.sk[t * KSEL + j] = a[j];
            }
            __syncthreads();
        }
        if (l < LUSED && t < KSEL) {
            keys_out[((size_t)(b * LL + l) * SPLIT + split) * KSEL + t] = shm.sk[t];
        }
        __syncthreads();                 // writes read before next row overwrites sk
    }
}

// Epilogue (verified, unchanged): merge the SPLIT partial top-5s per row, roll
// along L, min positional distance over the 5 selected pixels, mean.
__global__ __launch_bounds__(NTHREADS)
void finalize_kernel(const float* __restrict__ preds,
                     const ull* __restrict__ keys,
                     float* __restrict__ out) {
    const int t = threadIdx.x;
    float acc = 0.0f;

    for (int p = t; p < BS * LUSED; p += NTHREADS) {
        const int b = p / LUSED;
        const int l = p % LUSED + 1;              // loss rows: l = 1..63
        const float px = preds[b * (LL * 8) + l * 8 + 0];
        const float py = preds[b * (LL * 8) + l * 8 + 1];

        // tgt_down[:, l] = tgt[:, l-1]: merge the SPLIT sorted 5-lists of row l-1.
        const int srow = b * LL + (l - 1);
        ull loc[KSEL];
        #pragma unroll
        for (int j = 0; j < KSEL; ++j) loc[j] = SENTK;
        #pragma unroll
        for (int s = 0; s < SPLIT; ++s) {
            #pragma unroll
            for (int k = 0; k < KSEL; ++k) {
                sort_insert(loc, keys[((size_t)srow * SPLIT + s) * KSEL + k]);
            }
        }

        float best = 3.4028235e38f;
        #pragma unroll
        for (int k = 0; k < KSEL; ++k) {
            const int ixk = (int)(loc[k] & 0xFFFFFFFFULL);
            const float tx = (float)(ixk & 255) * (1.0f / 256.0f);   // exact /256
            const float ty = (float)(ixk >> 8) * (1.0f / 256.0f);
            const float dx = __fsub_rn(px, tx);
            const float dy = __fsub_rn(py, ty);
            const float dist = __fadd_rn(__fmul_rn(dx, dx), __fmul_rn(dy, dy));
            best = dist < best ? dist : best;
        }
        acc += best;
    }

    __shared__ float red[NTHREADS];
    red[t] = acc;
    __syncthreads();
    for (int s = NTHREADS / 2; s > 0; s >>= 1) {
        if (t < s) red[t] += red[t + s];
        __syncthreads();
    }
    if (t == 0) {
        out[0] = red[0] / (float)(BS * (LL - 1));
    }
}

extern "C" void kernel_launch(void* const* d_in, const int* in_sizes, int n_in,
                              void* d_out, int out_size, void* d_ws, size_t ws_size,
                              hipStream_t stream) {
    const float* preds = (const float*)d_in[0];   // (8, 64, 8) f32
    const float* imgs  = (const float*)d_in[1];   // (8, 3, 256, 256) f32
    float* out = (float*)d_out;                   // scalar f32
    ull* keys = (ull*)d_ws;                       // 512 * SPLIT * 5 u64 = 80 KB

    topk_kernel<<<dim3(NBLK2), dim3(NTHREADS), 0, stream>>>(preds, imgs, keys);
    finalize_kernel<<<dim3(1), dim3(NTHREADS), 0, stream>>>(preds, keys, out);
}

// Round 13
// 94.816 us; speedup vs baseline: 1.1436x; 1.1436x over previous
//
#include <hip/hip_runtime.h>

#define IMG_SIZE 256
#define NPIX (IMG_SIZE * IMG_SIZE)
#define KSEL 5
#define BS 8
#define LL 64
#define LUSED 63          // row l=63's top-k is discarded by the roll — never compute/write it
#define NTHREADS 256
#define SPLIT 4           // chunk splits per image (keys layout unchanged from champion)
#define CHUNK (NPIX / SPLIT)      // 16384 pixels per (b,split) slice
#define RPB 2             // rows (l values) amortized per block (R12 lesson: 4 starved waves)
#define RGRP (LL / RPB)   // 32 row-groups
#define NBLK2 (BS * SPLIT * RGRP)         // 1024 blocks = 4/CU x 4 waves = 16 waves/CU
#define QCAP 576          // per-wave tagged queue; 4*576*8 = 18432 B (>= sk, 8 blocks/CU LDS headroom)
#define SENTK 0xFFFFFFFFFFFFFFFFULL

typedef unsigned long long ull;

// Branchless sorted-insert: loc[] ascending; bubble key in, evict the max.
// Static indices only -> stays in VGPRs; no divergence.
__device__ __forceinline__ void sort_insert(ull loc[KSEL], ull key) {
    #pragma unroll
    for (int j = 0; j < KSEL; ++j) {
        const ull a = loc[j];
        const bool lt = key < a;
        loc[j] = lt ? key : a;
        key    = lt ? a : key;
    }
}

// Merge two ascending 5-lists, keep smallest 5 into a.
__device__ __forceinline__ void merge5(ull* a, const ull* b) {
    ull out[KSEL];
    int ia = 0, ib = 0;
    #pragma unroll
    for (int j = 0; j < KSEL; ++j) {
        const ull va = a[ia], vb = b[ib];
        const bool ta = va <= vb;
        out[j] = ta ? va : vb;
        ia += ta ? 1 : 0;
        ib += ta ? 0 : 1;
    }
    #pragma unroll
    for (int j = 0; j < KSEL; ++j) a[j] = out[j];
}

// Single source of truth for the SSD: match numpy f32 exactly — no FMA
// contraction, ((d0^2+d1^2)+d2^2). Bootstrap keys and steady-path gate both
// use THIS function, so gate-s and key-s are bit-identical.
__device__ __forceinline__ float
pix_s(float r0, float r1, float r2, float c0, float c1, float c2) {
    float d0 = __fsub_rn(r0, c0);
    float d1 = __fsub_rn(r1, c1);
    float d2 = __fsub_rn(r2, c2);
    return __fadd_rn(__fadd_rn(__fmul_rn(d0, d0), __fmul_rn(d1, d1)), __fmul_rn(d2, d2));
}

__device__ __forceinline__ ull
pix_key(float r0, float r1, float r2, float c0, float c1, float c2, int pix) {
    // s >= 0 (sum of squares) -> uint bit order == float order; low bits = pixel
    // index gives jax top_k's lower-index-first tie-break.
    const float s = pix_s(r0, r1, r2, c0, c1, c2);
    return ((ull)__float_as_uint(s) << 32) | (unsigned int)pix;
}

// One block per (b, split, row-pair). Verified R9 pipeline per row (bootstrap
// -> block-exact threshold -> gate-to-memory steady loop -> drain -> merge
// tree), image loads amortized over RPB=2 rows. Vs R12 (RPB=4, 51us): half
// the amortization but 2x the blocks (1024: 16 waves/CU, not 8) and LDS back
// to 18.5KB — the R12 failure was wave starvation, not the amortization idea.
// L2/L3 read volume: 396MB (R9) -> 198MB here. No XCD swizzle (R11 refuted
// the %8 mapping), no cross-block sync (R10), no divergent insert in the
// steady path (R7/R8).
// Queue entries carry a 1-bit row tag at bit 16 (pix < 2^16); pure key is
// reconstructed on drain, inserted via static 2-way branch (loc stays in
// registers). Exactness per row r (verified R8/R9/R12):
//   thr[r] = bits of 5th-smallest s over the 1024-px bootstrap >= s5_chunk;
//   admit iff bits(s) <= thr[r] => every true top-5 key is in bootstrap∪queue;
//   each pixel tested once per row, each queue entry inserted once
//   => bit-identical top-5 per (row, split).
__global__ __launch_bounds__(NTHREADS, 4)
void topk_kernel(const float* __restrict__ preds,
                 const float* __restrict__ imgs,
                 ull* __restrict__ keys_out) {
    const int blk = blockIdx.x;
    const int split = blk & (SPLIT - 1);
    const int q2 = blk >> 2;
    const int b = q2 & (BS - 1);
    const int rg = q2 >> 3;              // 0 .. RGRP-1
    const int t = threadIdx.x;
    const int wave = t >> 6;
    const int lane = t & 63;

    __shared__ union ShMem {
        ull qq[4][QCAP];                 // 18432 B: per-wave tagged queues
        ull sk[NTHREADS * KSEL];         // 10240 B: merge scratch (aliases qq)
    } shm;
    __shared__ unsigned wcnt[4];

    if (t < 4) wcnt[t] = 0u;

    const float* imgb = imgs + (size_t)b * 3 * NPIX;

    // Per-row pooled colors (verified scrambled indexing: flat i = l*bs + b).
    float c0v[RPB], c1v[RPB], c2v[RPB];
    #pragma unroll
    for (int r = 0; r < RPB; ++r) {
        const int l = rg * RPB + r;      // l = 63 computed, never written
        const int i = l * BS + b;
        const int pb = i >> 6;
        const int pl = i & 63;
        const float px = preds[pb * (LL * 8) + pl * 8 + 0];
        const float py = preds[pb * (LL * 8) + pl * 8 + 1];
        // grid_sample nearest, align_corners=False, zeros padding.
        const float cx = __fsub_rn(__fmul_rn(px, 256.0f), 0.5f);
        const float cy = __fsub_rn(__fmul_rn(py, 256.0f), 0.5f);
        const int ix = (int)rintf(cx);   // round half to even == jnp.rint
        const int iy = (int)rintf(cy);
        const bool valid = (ix >= 0) && (ix < IMG_SIZE) && (iy >= 0) && (iy < IMG_SIZE);
        const int ixc = min(max(ix, 0), IMG_SIZE - 1);
        const int iyc = min(max(iy, 0), IMG_SIZE - 1);
        const float vmul = valid ? 1.0f : 0.0f;
        c0v[r] = imgb[0 * NPIX + iyc * IMG_SIZE + ixc] * vmul;
        c1v[r] = imgb[1 * NPIX + iyc * IMG_SIZE + ixc] * vmul;
        c2v[r] = imgb[2 * NPIX + iyc * IMG_SIZE + ixc] * vmul;
    }

    const float4* p0 = (const float4*)(imgb + 0 * NPIX);
    const float4* p1 = (const float4*)(imgb + 1 * NPIX);
    const float4* p2 = (const float4*)(imgb + 2 * NPIX);

    ull loc[RPB][KSEL];                  // unrolled row loops -> registers
    #pragma unroll
    for (int r = 0; r < RPB; ++r)
        #pragma unroll
        for (int j = 0; j < KSEL; ++j) loc[r][j] = SENTK;

    const int v0 = split * (CHUNK / 4);

    // ---- Bootstrap: iteration 0 (1024 px), unconditional inserts x 2 rows ----
    {
        const int v = v0 + t;
        const float4 r0 = p0[v];
        const float4 r1 = p1[v];
        const float4 r2 = p2[v];
        const int base = v * 4;
        #pragma unroll
        for (int r = 0; r < RPB; ++r) {
            sort_insert(loc[r], pix_key(r0.x, r1.x, r2.x, c0v[r], c1v[r], c2v[r], base + 0));
            sort_insert(loc[r], pix_key(r0.y, r1.y, r2.y, c0v[r], c1v[r], c2v[r], base + 1));
            sort_insert(loc[r], pix_key(r0.z, r1.z, r2.z, c0v[r], c1v[r], c2v[r], base + 2));
            sort_insert(loc[r], pix_key(r0.w, r1.w, r2.w, c0v[r], c1v[r], c2v[r], base + 3));
        }
    }

    // ---- Per-row block-exact bootstrap thresholds (verified merge5 tree x2) ----
    unsigned thrv[RPB];
    __syncthreads();                     // wcnt init + before first sk use
    #pragma unroll
    for (int r = 0; r < RPB; ++r) {
        #pragma unroll
        for (int j = 0; j < KSEL; ++j) shm.sk[t * KSEL + j] = loc[r][j];
        __syncthreads();
        for (int s = NTHREADS / 2; s > 0; s >>= 1) {
            if (t < s) {
                ull a[KSEL], bb[KSEL];
                #pragma unroll
                for (int j = 0; j < KSEL; ++j) { a[j] = shm.sk[t * KSEL + j]; bb[j] = shm.sk[(t + s) * KSEL + j]; }
                merge5(a, bb);
                #pragma unroll
                for (int j = 0; j < KSEL; ++j) shm.sk[t * KSEL + j] = a[j];
            }
            __syncthreads();
        }
        thrv[r] = (unsigned)(shm.sk[KSEL - 1] >> 32);   // bits of s5(bootstrap, row r)
        __syncthreads();                 // all read sk[4] before next overwrite
    }
    if (t < 4) wcnt[t] = 0u;             // queue region (aliases sk) about to be used
    __syncthreads();

    // Drain helper: pop tagged entries into the right row list (static branch).
    auto drain = [&]() {
        const unsigned n = wcnt[wave];
        for (unsigned o = lane; o < n; o += 64) {
            const ull e = shm.qq[wave][o];
            const ull key = (e & 0xFFFFFFFF00000000ULL) | (e & 0xFFFFULL);
            if (((e >> 16) & 1ULL) == 0) sort_insert(loc[0], key);
            else                         sort_insert(loc[1], key);
        }
    };

    // ---- Steady loop: dense loads amortized over 2 rows; 9-op s per row;
    //      rare tagged queue push (no insert, no ballot in the hot path) ----
    #pragma unroll 2
    for (int it = 1; it < CHUNK / 4 / NTHREADS; ++it) {
        // Overflow safety (wave-uniform; worst case 64 lanes*4px*2rows = 512/iter).
        if (wcnt[wave] > QCAP - 2 * NTHREADS) {
            drain();
            if (lane == 0) wcnt[wave] = 0u;   // per-wave LDS ops in order: reads precede
        }
        const int v = v0 + it * NTHREADS + t;
        const float4 r0 = p0[v];
        const float4 r1 = p1[v];
        const float4 r2 = p2[v];
        const int base = v * 4;

        #pragma unroll
        for (int r = 0; r < RPB; ++r) {
            const float s0 = pix_s(r0.x, r1.x, r2.x, c0v[r], c1v[r], c2v[r]);
            const float s1 = pix_s(r0.y, r1.y, r2.y, c0v[r], c1v[r], c2v[r]);
            const float s2 = pix_s(r0.z, r1.z, r2.z, c0v[r], c1v[r], c2v[r]);
            const float s3 = pix_s(r0.w, r1.w, r2.w, c0v[r], c1v[r], c2v[r]);
            if (__float_as_uint(s0) <= thrv[r]) {
                const unsigned pos = atomicAdd(&wcnt[wave], 1u);
                shm.qq[wave][pos] = ((ull)__float_as_uint(s0) << 32) | ((ull)r << 16) | (unsigned)(base + 0);
            }
            if (__float_as_uint(s1) <= thrv[r]) {
                const unsigned pos = atomicAdd(&wcnt[wave], 1u);
                shm.qq[wave][pos] = ((ull)__float_as_uint(s1) << 32) | ((ull)r << 16) | (unsigned)(base + 1);
            }
            if (__float_as_uint(s2) <= thrv[r]) {
                const unsigned pos = atomicAdd(&wcnt[wave], 1u);
                shm.qq[wave][pos] = ((ull)__float_as_uint(s2) << 32) | ((ull)r << 16) | (unsigned)(base + 2);
            }
            if (__float_as_uint(s3) <= thrv[r]) {
                const unsigned pos = atomicAdd(&wcnt[wave], 1u);
                shm.qq[wave][pos] = ((ull)__float_as_uint(s3) << 32) | ((ull)r << 16) | (unsigned)(base + 3);
            }
        }
    }

    // ---- End drain, then per-row verified merge trees + key output ----
    drain();
    __syncthreads();                     // all drains done before sk (alias) reuse
    #pragma unroll
    for (int r = 0; r < RPB; ++r) {
        const int l = rg * RPB + r;
        #pragma unroll
        for (int j = 0; j < KSEL; ++j) shm.sk[t * KSEL + j] = loc[r][j];
        __syncthreads();
        for (int s = NTHREADS / 2; s > 0; s >>= 1) {
            if (t < s) {
                ull a[KSEL], bb[KSEL];
                #pragma unroll
                for (int j = 0; j < KSEL; ++j) { a[j] = shm.sk[t * KSEL + j]; bb[j] = shm.sk[(t + s) * KSEL + j]; }
                merge5(a, bb);
                #pragma unroll
                for (int j = 0; j < KSEL; ++j) shm.sk[t * KSEL + j] = a[j];
            }
            __syncthreads();
        }
        if (l < LUSED && t < KSEL) {
            keys_out[((size_t)(b * LL + l) * SPLIT + split) * KSEL + t] = shm.sk[t];
        }
        __syncthreads();                 // writes read before next row overwrites sk
    }
}

// Epilogue (verified, unchanged): merge the SPLIT partial top-5s per row, roll
// along L, min positional distance over the 5 selected pixels, mean.
__global__ __launch_bounds__(NTHREADS)
void finalize_kernel(const float* __restrict__ preds,
                     const ull* __restrict__ keys,
                     float* __restrict__ out) {
    const int t = threadIdx.x;
    float acc = 0.0f;

    for (int p = t; p < BS * LUSED; p += NTHREADS) {
        const int b = p / LUSED;
        const int l = p % LUSED + 1;              // loss rows: l = 1..63
        const float px = preds[b * (LL * 8) + l * 8 + 0];
        const float py = preds[b * (LL * 8) + l * 8 + 1];

        // tgt_down[:, l] = tgt[:, l-1]: merge the SPLIT sorted 5-lists of row l-1.
        const int srow = b * LL + (l - 1);
        ull loc[KSEL];
        #pragma unroll
        for (int j = 0; j < KSEL; ++j) loc[j] = SENTK;
        #pragma unroll
        for (int s = 0; s < SPLIT; ++s) {
            #pragma unroll
            for (int k = 0; k < KSEL; ++k) {
                sort_insert(loc, keys[((size_t)srow * SPLIT + s) * KSEL + k]);
            }
        }

        float best = 3.4028235e38f;
        #pragma unroll
        for (int k = 0; k < KSEL; ++k) {
            const int ixk = (int)(loc[k] & 0xFFFFFFFFULL);
            const float tx = (float)(ixk & 255) * (1.0f / 256.0f);   // exact /256
            const float ty = (float)(ixk >> 8) * (1.0f / 256.0f);
            const float dx = __fsub_rn(px, tx);
            const float dy = __fsub_rn(py, ty);
            const float dist = __fadd_rn(__fmul_rn(dx, dx), __fmul_rn(dy, dy));
            best = dist < best ? dist : best;
        }
        acc += best;
    }

    __shared__ float red[NTHREADS];
    red[t] = acc;
    __syncthreads();
    for (int s = NTHREADS / 2; s > 0; s >>= 1) {
        if (t < s) red[t] += red[t + s];
        __syncthreads();
    }
    if (t == 0) {
        out[0] = red[0] / (float)(BS * (LL - 1));
    }
}

extern "C" void kernel_launch(void* const* d_in, const int* in_sizes, int n_in,
                              void* d_out, int out_size, void* d_ws, size_t ws_size,
                              hipStream_t stream) {
    const float* preds = (const float*)d_in[0];   // (8, 64, 8) f32
    const float* imgs  = (const float*)d_in[1];   // (8, 3, 256, 256) f32
    float* out = (float*)d_out;                   // scalar f32
    ull* keys = (ull*)d_ws;                       // 512 * SPLIT * 5 u64 = 80 KB

    topk_kernel<<<dim3(NBLK2), dim3(NTHREADS), 0, stream>>>(preds, imgs, keys);
    finalize_kernel<<<dim3(1), dim3(NTHREADS), 0, stream>>>(preds, keys, out);
}